// Round 6
// baseline (384.817 us; speedup 1.0000x reference)
//
#include <hip/hip_runtime.h>

#define B_ 4
#define N_ 4096
#define D_ 1536
#define H_ 512
#define K_ 8
#define M_ (B_*N_)          // 16384
#define R2_ 160000.0f       // 400^2
#define CAP 192             // max neighbors per node (mean deg ~32, P(>192)~0)

typedef __attribute__((ext_vector_type(8))) short bf16x8;
typedef __attribute__((ext_vector_type(4))) float f32x4;

__device__ __forceinline__ unsigned short f2bf(float f) {
  union { float f; unsigned u; } v; v.f = f;
  unsigned r = (v.u + 0x7FFFu + ((v.u >> 16) & 1u)) >> 16;
  return (unsigned short)r;
}

typedef const __attribute__((address_space(1))) unsigned int gas_u32;
typedef __attribute__((address_space(3))) unsigned int las_u32;
__device__ __forceinline__ void gl_lds16(const void* g, void* l) {
  __builtin_amdgcn_global_load_lds((gas_u32*)g, (las_u32*)l, 16, 0, 0);
}

// ---------------- K0: prep — anchor norms + weight transposes ----------------
__global__ __launch_bounds__(256) void k_prep(
    const float* __restrict__ Wf, const float* __restrict__ Wg, const float* __restrict__ Ws,
    const float* __restrict__ anchors, unsigned short* __restrict__ WfT,
    unsigned short* __restrict__ WgsT, float* __restrict__ anorm) {
  __shared__ float t[64][65];
  __shared__ float red[4];
  int bx = blockIdx.x, by = blockIdx.y, tid = threadIdx.x;
  if (by == 40) {
    int k = bx;
    float s = 0.f;
    for (int i = tid; i < D_; i += 256) { float v = anchors[k*D_ + i]; s += v*v; }
    #pragma unroll
    for (int off = 32; off; off >>= 1) s += __shfl_down(s, off);
    if ((tid & 63) == 0) red[tid >> 6] = s;
    __syncthreads();
    if (tid == 0) anorm[k] = fmaxf(sqrtf(red[0]+red[1]+red[2]+red[3]), 1e-12f);
    return;
  }
  const float* W; unsigned short* WT; int kt, outStride, outOff;
  if (by < 24)      { W = Wf; WT = WfT;  kt = by;      outStride = D_;   outOff = 0; }
  else if (by < 32) { W = Wg; WT = WgsT; kt = by - 24; outStride = 1024; outOff = 0; }
  else              { W = Ws; WT = WgsT; kt = by - 32; outStride = 1024; outOff = 512; }
  int tx = tid & 63, ty = tid >> 6;
  #pragma unroll
  for (int r = 0; r < 64; r += 4)
    t[ty + r][tx] = W[(size_t)(kt*64 + ty + r)*H_ + bx*64 + tx];
  __syncthreads();
  #pragma unroll
  for (int r = 0; r < 64; r += 4) {
    int n = bx*64 + ty + r;
    WT[(size_t)n*outStride + outOff + kt*64 + tx] = f2bf(t[tx][ty + r]);
  }
}

// ---------------- K1: fused GEMM1 (feat) + concept stream ----------------
// C(16384x512) = bf16(images) @ WfT^T, epilogue + pos-encoding -> AB[:,512:1024)
// bn==4 blocks: sumsq (f32 exact) + anchor dots from the same LDS A-tiles -> out[512:520)
#define BM 128
#define BK 32

__global__ __launch_bounds__(256) void k_gemm1f(
    const float* __restrict__ images, const unsigned short* __restrict__ WfT,
    const float* __restrict__ bias, const float* __restrict__ Wpos,
    const float* __restrict__ positions, const float* __restrict__ anchors,
    const float* __restrict__ anorm, unsigned short* __restrict__ AB,
    float* __restrict__ out) {
  __shared__ float Asf[BM*BK];             // 16 KB, XOR-swizzled f32 A-tile
  __shared__ unsigned short Bsh[12288];    // 24 KB: B-tile (8 KB) or bf16 anchors (24 KB)
  __shared__ float sConc[8];
  int tid = threadIdx.x, lane = tid & 63, wv = tid >> 6;
  int l15 = lane & 15, quad = lane >> 4;
  int bx = blockIdx.x;
  int xcd = bx & 7, idx = bx >> 3;         // 5 bn-blocks of one bm share an XCD (L2 reuse)
  int q5 = idx / 5;
  int bm = xcd*16 + q5, bn = idx - q5*5;
  int m0 = bm*BM;
  bool isC = (bn == 4);
  int n0 = bn*128;

  // A-DMA lane mapping: LDS side is lane-contiguous; global side XOR-permuted so that
  // physical quad p at row r holds logical k-quad (p ^ (r&3)) -> frag reads spread banks.
  int r8 = lane >> 3, qp = (lane & 7) >> 1, rem = (lane & 1)*4;
  int lw = ((qp ^ (r8 & 3)) << 3) + rem;
  const float* gA = images + (size_t)(m0 + wv*32 + r8)*D_ + lw;
  float* lA = Asf + wv*32*BK;

  const unsigned short* gB = WfT + (size_t)(n0 + wv*32 + (lane >> 2))*D_ + (lane & 3)*8;
  unsigned short* lB = Bsh + wv*32*BK;

  if (isC) {
    for (int i = tid; i < 3072; i += 256) {        // 12288 f32 -> bf16 anchors in LDS
      float4 a = ((const float4*)anchors)[i];
      ushort4 s; s.x = f2bf(a.x); s.y = f2bf(a.y); s.z = f2bf(a.z); s.w = f2bf(a.w);
      ((ushort4*)Bsh)[i] = s;
    }
  }
  if (tid < 8) sConc[tid] = 0.f;

  f32x4 acc[4][4] = {};
  float dk[8] = {};
  float ss = 0.f;
  int wm = wv >> 1, wn = wv & 1;
  int crow = tid >> 1, ch = tid & 1;
  int cs0 = (((2*ch)   ^ (crow & 3)) << 3);
  int cs1 = (((2*ch+1) ^ (crow & 3)) << 3);
  const float* crp = &Asf[crow*BK];

  for (int kt = 0; kt < 48; kt++) {
    __syncthreads();
    #pragma unroll
    for (int t = 0; t < 4; t++)
      gl_lds16(gA + (size_t)t*8*D_, lA + t*8*BK);
    if (!isC) {
      gl_lds16(gB, lB);
      gl_lds16(gB + (size_t)16*D_, lB + 16*BK);
    }
    gA += BK; gB += BK;
    __syncthreads();

    if (!isC) {
      bf16x8 aF[4], bF[4];
      #pragma unroll
      for (int f = 0; f < 4; f++) {
        int row = wm*64 + f*16 + l15;
        const float* ap = &Asf[row*BK + ((quad ^ (row & 3)) << 3)];
        float4 x0 = *(const float4*)ap;
        float4 x1 = *(const float4*)(ap + 4);
        bf16x8 v;
        v[0] = f2bf(x0.x); v[1] = f2bf(x0.y); v[2] = f2bf(x0.z); v[3] = f2bf(x0.w);
        v[4] = f2bf(x1.x); v[5] = f2bf(x1.y); v[6] = f2bf(x1.z); v[7] = f2bf(x1.w);
        aF[f] = v;
      }
      #pragma unroll
      for (int f = 0; f < 4; f++)
        bF[f] = *(const bf16x8*)&Bsh[(wn*64 + f*16 + l15)*BK + quad*8];
      #pragma unroll
      for (int mi = 0; mi < 4; mi++)
        #pragma unroll
        for (int ni = 0; ni < 4; ni++)
          acc[mi][ni] = __builtin_amdgcn_mfma_f32_16x16x32_bf16(aF[mi], bF[ni], acc[mi][ni], 0, 0, 0);
    } else {
      float4 x0 = *(const float4*)(crp + cs0);
      float4 x1 = *(const float4*)(crp + cs0 + 4);
      float4 x2 = *(const float4*)(crp + cs1);
      float4 x3 = *(const float4*)(crp + cs1 + 4);
      ss += x0.x*x0.x + x0.y*x0.y + x0.z*x0.z + x0.w*x0.w
          + x1.x*x1.x + x1.y*x1.y + x1.z*x1.z + x1.w*x1.w
          + x2.x*x2.x + x2.y*x2.y + x2.z*x2.z + x2.w*x2.w
          + x3.x*x3.x + x3.y*x3.y + x3.z*x3.z + x3.w*x3.w;
      const unsigned short* abase = &Bsh[kt*32 + ch*16];
      #pragma unroll
      for (int k = 0; k < 8; k++) {
        uint4 a0 = *(const uint4*)(abase + (size_t)k*D_);
        uint4 a1 = *(const uint4*)(abase + (size_t)k*D_ + 8);
        union { unsigned u; float f; } c;
        float s = 0.f;
        c.u = a0.x << 16;         s += x0.x*c.f;
        c.u = a0.x & 0xFFFF0000u; s += x0.y*c.f;
        c.u = a0.y << 16;         s += x0.z*c.f;
        c.u = a0.y & 0xFFFF0000u; s += x0.w*c.f;
        c.u = a0.z << 16;         s += x1.x*c.f;
        c.u = a0.z & 0xFFFF0000u; s += x1.y*c.f;
        c.u = a0.w << 16;         s += x1.z*c.f;
        c.u = a0.w & 0xFFFF0000u; s += x1.w*c.f;
        c.u = a1.x << 16;         s += x2.x*c.f;
        c.u = a1.x & 0xFFFF0000u; s += x2.y*c.f;
        c.u = a1.y << 16;         s += x2.z*c.f;
        c.u = a1.y & 0xFFFF0000u; s += x2.w*c.f;
        c.u = a1.z << 16;         s += x3.x*c.f;
        c.u = a1.z & 0xFFFF0000u; s += x3.y*c.f;
        c.u = a1.w << 16;         s += x3.z*c.f;
        c.u = a1.w & 0xFFFF0000u; s += x3.w*c.f;
        dk[k] += s;
      }
    }
  }

  if (!isC) {
    float bz[4], w0v[4], w1v[4];
    #pragma unroll
    for (int ni = 0; ni < 4; ni++) {
      int gh = n0 + wn*64 + ni*16 + l15;
      bz[ni] = bias[gh]; w0v[ni] = Wpos[gh]; w1v[ni] = Wpos[H_ + gh];
    }
    #pragma unroll
    for (int mi = 0; mi < 4; mi++) {
      #pragma unroll
      for (int r = 0; r < 4; r++) {
        int gm = m0 + wm*64 + mi*16 + quad*4 + r;
        float2 p = ((const float2*)positions)[gm];
        #pragma unroll
        for (int ni = 0; ni < 4; ni++) {
          int gh = n0 + wn*64 + ni*16 + l15;
          float v = acc[mi][ni][r] + bz[ni] + p.x*w0v[ni] + p.y*w1v[ni];
          AB[(size_t)gm*1024 + 512 + gh] = f2bf(v);
        }
      }
    }
  } else {
    #pragma unroll
    for (int k = 0; k < 8; k++) dk[k] += __shfl_xor(dk[k], 1);
    ss += __shfl_xor(ss, 1);
    if (ch == 0) {
      float inv = 1.0f / fmaxf(sqrtf(ss), 1e-12f);
      #pragma unroll
      for (int k = 0; k < 8; k++) atomicAdd(&sConc[k], dk[k]*inv / anorm[k]);
    }
    __syncthreads();
    if (tid < 8) atomicAdd(out + (m0 >> 12)*(H_+K_) + H_ + tid, sConc[tid]*(1.0f/N_));
  }
}

// ---------------- K2: GEMM2 — out-pool = mean relu([agg|feat] @ [Wg;Ws]) ----------------
__global__ __launch_bounds__(256) void k_gemm2(
    const unsigned short* __restrict__ A, const unsigned short* __restrict__ BT,
    float* __restrict__ out) {
  __shared__ unsigned short As[BM*BK];
  __shared__ unsigned short Bs[128*BK];
  __shared__ float colsum[128];
  int tid = threadIdx.x;
  int lane = tid & 63, wv = tid >> 6;
  int wm = wv >> 1, wn = wv & 1;
  int l15 = lane & 15, quad = lane >> 4;
  int bx = blockIdx.x;
  int xcd = bx & 7, idx = bx >> 3;     // 4 bn-blocks of one bm share an XCD
  int bm = xcd*16 + (idx >> 2), bn = idx & 3;
  int m0 = bm*BM, n0 = bn*128;

  f32x4 acc[4][4] = {};

  int c = wv*2;
  int rowc = (lane >> 2), seg = lane & 3;
  const unsigned short* gA0 = A + (size_t)(m0 + c*16 + rowc)*1024 + seg*8;
  const unsigned short* gA1 = gA0 + (size_t)16*1024;
  const unsigned short* gB0 = BT + (size_t)(n0 + c*16 + rowc)*1024 + seg*8;
  const unsigned short* gB1 = gB0 + (size_t)16*1024;
  unsigned short* lA0 = As + c*512;
  unsigned short* lA1 = lA0 + 512;
  unsigned short* lB0 = Bs + c*512;
  unsigned short* lB1 = lB0 + 512;

  for (int kt = 0; kt < 32; kt++) {
    __syncthreads();
    gl_lds16(gA0, lA0); gl_lds16(gA1, lA1);
    gl_lds16(gB0, lB0); gl_lds16(gB1, lB1);
    gA0 += BK; gA1 += BK; gB0 += BK; gB1 += BK;
    __syncthreads();

    bf16x8 aF[4], bF[4];
    #pragma unroll
    for (int f = 0; f < 4; f++)
      aF[f] = *(const bf16x8*)&As[(wm*64 + f*16 + l15)*BK + quad*8];
    #pragma unroll
    for (int f = 0; f < 4; f++)
      bF[f] = *(const bf16x8*)&Bs[(wn*64 + f*16 + l15)*BK + quad*8];
    #pragma unroll
    for (int mi = 0; mi < 4; mi++)
      #pragma unroll
      for (int ni = 0; ni < 4; ni++)
        acc[mi][ni] = __builtin_amdgcn_mfma_f32_16x16x32_bf16(aF[mi], bF[ni], acc[mi][ni], 0, 0, 0);
  }

  if (tid < 128) colsum[tid] = 0.f;
  __syncthreads();
  #pragma unroll
  for (int ni = 0; ni < 4; ni++) {
    float s = 0.f;
    #pragma unroll
    for (int mi = 0; mi < 4; mi++) {
      #pragma unroll
      for (int r = 0; r < 4; r++) s += fmaxf(acc[mi][ni][r], 0.f);
    }
    s += __shfl_down(s, 32);
    s += __shfl_down(s, 16);
    if (quad == 0) atomicAdd(&colsum[wn*64 + ni*16 + l15], s);
  }
  __syncthreads();
  if (tid < 128) {
    int b = m0 >> 12;
    atomicAdd(out + b*(H_+K_) + n0 + tid, colsum[tid] * (1.0f/N_));
  }
}

// ---------------- K3a: adjacency build — nlist[gm][CAP] + deg[gm] ----------------
__global__ __launch_bounds__(256) void k_adjacency(const float* __restrict__ positions,
                                                   unsigned short* __restrict__ nlistG,
                                                   int* __restrict__ degG) {
  __shared__ float sdx[32], sdy[32];
  __shared__ int cnt[32];
  __shared__ unsigned short nl[32*CAP];
  int blk = blockIdx.x;
  int xcd = blk & 7;
  int b = xcd >> 1;
  int sub = ((blk >> 3) << 1) | (xcd & 1);
  int dest0 = sub * 32;
  int tid = threadIdx.x;
  const float2* p2 = (const float2*)(positions + (size_t)b*N_*2);
  if (tid < 32) {
    cnt[tid] = 0;
    float2 pd = p2[dest0 + tid];
    sdx[tid] = pd.x; sdy[tid] = pd.y;
  }
  __syncthreads();
  for (int it = 0; it < 16; it++) {
    int j = tid + 256*it;
    float2 pj = p2[j];
    #pragma unroll
    for (int d = 0; d < 32; d++) {
      float dx = pj.x - sdx[d], dy = pj.y - sdy[d];
      if (dx*dx + dy*dy < R2_ && j != dest0 + d) {
        int p = atomicAdd(&cnt[d], 1);
        if (p < CAP) nl[d*CAP + p] = (unsigned short)j;
      }
    }
  }
  __syncthreads();
  int gd0 = (b << 12) + dest0;
  uint4* dst = (uint4*)(nlistG + (size_t)gd0*CAP);
  const uint4* src = (const uint4*)nl;
  #pragma unroll
  for (int i = 0; i < 3; i++) dst[tid + 256*i] = src[tid + 256*i];
  if (tid < 32) degG[gd0 + tid] = min(cnt[tid], CAP);
}

// ---------------- K3b: mean aggregation of relu(feat), ILP-4 gather ----------------
__device__ __forceinline__ void acc8(uint4 v, float* a) {
  union { unsigned u; float f; } t;
  t.u = v.x << 16;          a[0] += fmaxf(t.f, 0.f);
  t.u = v.x & 0xFFFF0000u;  a[1] += fmaxf(t.f, 0.f);
  t.u = v.y << 16;          a[2] += fmaxf(t.f, 0.f);
  t.u = v.y & 0xFFFF0000u;  a[3] += fmaxf(t.f, 0.f);
  t.u = v.z << 16;          a[4] += fmaxf(t.f, 0.f);
  t.u = v.z & 0xFFFF0000u;  a[5] += fmaxf(t.f, 0.f);
  t.u = v.w << 16;          a[6] += fmaxf(t.f, 0.f);
  t.u = v.w & 0xFFFF0000u;  a[7] += fmaxf(t.f, 0.f);
}

__global__ __launch_bounds__(256) void k_aggregate(const unsigned short* __restrict__ nlistG,
                                                   const int* __restrict__ degG,
                                                   unsigned short* __restrict__ AB) {
  __shared__ unsigned short nl[8*CAP];
  __shared__ int dg[8];
  int blk = blockIdx.x;
  int xcd = blk & 7;
  int b = xcd >> 1;
  int sub = ((blk >> 3) << 1) | (xcd & 1);
  int dest0 = sub * 8;
  int gd0 = (b << 12) + dest0;
  int tid = threadIdx.x, lane = tid & 63, w = tid >> 6;
  if (tid < 192) ((uint4*)nl)[tid] = ((const uint4*)(nlistG + (size_t)gd0*CAP))[tid];
  if (tid < 8) dg[tid] = degG[gd0 + tid];
  __syncthreads();
  const unsigned short* featb = AB + ((size_t)(b << 12))*1024 + 512 + lane*8;
  #pragma unroll
  for (int dd = 0; dd < 2; dd++) {
    int d = w*2 + dd;
    int deg = dg[d];
    float inv = 1.0f / (float)(deg > 1 ? deg : 1);
    const unsigned short* nlp = &nl[d*CAP];
    float a[8] = {};
    int n = 0;
    for (; n + 4 <= deg; n += 4) {
      ushort4 idx = *(const ushort4*)&nlp[n];
      uint4 v0 = *(const uint4*)(featb + (size_t)idx.x*1024);
      uint4 v1 = *(const uint4*)(featb + (size_t)idx.y*1024);
      uint4 v2 = *(const uint4*)(featb + (size_t)idx.z*1024);
      uint4 v3 = *(const uint4*)(featb + (size_t)idx.w*1024);
      acc8(v0, a); acc8(v1, a); acc8(v2, a); acc8(v3, a);
    }
    for (; n < deg; n++) {
      int j = nlp[n];
      uint4 v = *(const uint4*)(featb + (size_t)j*1024);
      acc8(v, a);
    }
    uint4 o;
    o.x = ((unsigned)f2bf(a[1]*inv) << 16) | f2bf(a[0]*inv);
    o.y = ((unsigned)f2bf(a[3]*inv) << 16) | f2bf(a[2]*inv);
    o.z = ((unsigned)f2bf(a[5]*inv) << 16) | f2bf(a[4]*inv);
    o.w = ((unsigned)f2bf(a[7]*inv) << 16) | f2bf(a[6]*inv);
    *(uint4*)(AB + (size_t)(gd0 + d)*1024 + lane*8) = o;
  }
}

extern "C" void kernel_launch(void* const* d_in, const int* in_sizes, int n_in,
                              void* d_out, int out_size, void* d_ws, size_t ws_size,
                              hipStream_t stream) {
  const float* images    = (const float*)d_in[0];
  const float* positions = (const float*)d_in[1];
  const float* W_feat    = (const float*)d_in[2];
  const float* b_feat    = (const float*)d_in[3];
  const float* W_pos     = (const float*)d_in[4];
  const float* W_gnn     = (const float*)d_in[5];
  const float* W_self    = (const float*)d_in[6];
  const float* anchors   = (const float*)d_in[7];
  float* out = (float*)d_out;

  char* ws = (char*)d_ws;
  unsigned short* nlistG  = (unsigned short*)ws;                     // 16384*CAP*2 = 6291456
  int*            degG    = (int*)(ws + 6291456);                    // 65536
  unsigned short* AB      = (unsigned short*)(ws + 50331648);        // 16384*1024*2
  unsigned short* WfT     = (unsigned short*)(ws + 83886080);        // 512*1536*2
  unsigned short* WgsT    = (unsigned short*)(ws + 85458944);        // 512*1024*2
  float*          anorm   = (float*)(ws + 86507520);                 // 8*4

  hipMemsetAsync(d_out, 0, sizeof(float)*B_*(H_+K_), stream);
  k_prep<<<dim3(8, 41), 256, 0, stream>>>(W_feat, W_gnn, W_self, anchors, WfT, WgsT, anorm);
  k_gemm1f<<<640, 256, 0, stream>>>(images, WfT, b_feat, W_pos, positions, anchors, anorm, AB, out);
  k_adjacency<<<512, 256, 0, stream>>>(positions, nlistG, degG);
  k_aggregate<<<2048, 256, 0, stream>>>(nlistG, degG, AB);
  k_gemm2<<<512, 256, 0, stream>>>(AB, WgsT, out);
}

// Round 7
// 310.471 us; speedup vs baseline: 1.2395x; 1.2395x over previous
//
#include <hip/hip_runtime.h>

#define B_ 4
#define N_ 4096
#define D_ 1536
#define H_ 512
#define K_ 8
#define M_ (B_*N_)          // 16384
#define R2_ 160000.0f       // 400^2
#define CAP 192             // max neighbors tracked per node (mean deg ~32, P(>192)~0)

typedef __attribute__((ext_vector_type(8))) short bf16x8;
typedef __attribute__((ext_vector_type(4))) float f32x4;

__device__ __forceinline__ unsigned short f2bf(float f) {
  union { float f; unsigned u; } v; v.f = f;
  unsigned r = (v.u + 0x7FFFu + ((v.u >> 16) & 1u)) >> 16;
  return (unsigned short)r;
}

typedef const __attribute__((address_space(1))) unsigned int gas_u32;
typedef __attribute__((address_space(3))) unsigned int las_u32;
__device__ __forceinline__ void gl_lds16(const unsigned short* g, unsigned short* l) {
  __builtin_amdgcn_global_load_lds((gas_u32*)g, (las_u32*)l, 16, 0, 0);
}

// ---------------- K0: prep — anchor norms + all weight transposes (one launch) ----------
__global__ __launch_bounds__(256) void k_prep(
    const float* __restrict__ Wf, const float* __restrict__ Wg, const float* __restrict__ Ws,
    const float* __restrict__ anchors, unsigned short* __restrict__ WfT,
    unsigned short* __restrict__ WgsT, float* __restrict__ anorm) {
  __shared__ float t[64][65];
  __shared__ float red[4];
  int bx = blockIdx.x, by = blockIdx.y, tid = threadIdx.x;
  if (by == 40) {
    int k = bx;
    float s = 0.f;
    for (int i = tid; i < D_; i += 256) { float v = anchors[k*D_ + i]; s += v*v; }
    #pragma unroll
    for (int off = 32; off; off >>= 1) s += __shfl_down(s, off);
    if ((tid & 63) == 0) red[tid >> 6] = s;
    __syncthreads();
    if (tid == 0) anorm[k] = fmaxf(sqrtf(red[0]+red[1]+red[2]+red[3]), 1e-12f);
    return;
  }
  const float* W; unsigned short* WT; int kt, outStride, outOff;
  if (by < 24)      { W = Wf; WT = WfT;  kt = by;      outStride = D_;   outOff = 0; }
  else if (by < 32) { W = Wg; WT = WgsT; kt = by - 24; outStride = 1024; outOff = 0; }
  else              { W = Ws; WT = WgsT; kt = by - 32; outStride = 1024; outOff = 512; }
  int tx = tid & 63, ty = tid >> 6;
  #pragma unroll
  for (int r = 0; r < 64; r += 4)
    t[ty + r][tx] = W[(size_t)(kt*64 + ty + r)*H_ + bx*64 + tx];
  __syncthreads();
  #pragma unroll
  for (int r = 0; r < 64; r += 4) {
    int n = bx*64 + ty + r;
    WT[(size_t)n*outStride + outOff + kt*64 + tx] = f2bf(t[tx][ty + r]);
  }
}

// ---------------- K1: concept scores + images f32->bf16 cast (LDS-staged anchors) ----------------
__global__ __launch_bounds__(256) void k_concept_cast(
    const float* __restrict__ images, const float* __restrict__ anchors,
    const float* __restrict__ anorm, unsigned short* __restrict__ imgs_bf,
    float* __restrict__ out) {
  __shared__ float sA[K_*D_];     // 48 KB
  __shared__ float sc[4][K_];
  int tid = threadIdx.x, lane = tid & 63, w = tid >> 6;
  {
    const float4* a4 = (const float4*)anchors;
    float4* sA4 = (float4*)sA;
    #pragma unroll
    for (int i = 0; i < 12; i++) sA4[tid + 256*i] = a4[tid + 256*i];
  }
  __syncthreads();
  float acc_k[K_] = {};
  for (int r = 0; r < 8; r++) {
    int gm = blockIdx.x*32 + w*8 + r;
    const float4* xrow = (const float4*)(images + (size_t)gm*D_);
    float nrm = 0.f; float dot[K_] = {};
    #pragma unroll
    for (int it = 0; it < 6; it++) {
      int j = lane + 64*it;
      float4 x = xrow[j];
      nrm += x.x*x.x + x.y*x.y + x.z*x.z + x.w*x.w;
      #pragma unroll
      for (int k = 0; k < K_; k++) {
        float4 a = *(const float4*)&sA[(size_t)(k*384 + j)*4];
        dot[k] += x.x*a.x + x.y*a.y + x.z*a.z + x.w*a.w;
      }
      ushort4 s;
      s.x = f2bf(x.x); s.y = f2bf(x.y); s.z = f2bf(x.z); s.w = f2bf(x.w);
      *(ushort4*)&imgs_bf[(size_t)gm*D_ + (size_t)j*4] = s;
    }
    #pragma unroll
    for (int off = 32; off; off >>= 1) {
      nrm += __shfl_down(nrm, off);
      #pragma unroll
      for (int k = 0; k < K_; k++) dot[k] += __shfl_down(dot[k], off);
    }
    if (lane == 0) {
      float inv = 1.0f / fmaxf(sqrtf(nrm), 1e-12f);
      #pragma unroll
      for (int k = 0; k < K_; k++) acc_k[k] += dot[k] * inv / anorm[k];
    }
  }
  if (lane == 0) {
    #pragma unroll
    for (int k = 0; k < K_; k++) sc[w][k] = acc_k[k];
  }
  __syncthreads();
  if (tid < K_) {
    float s = sc[0][tid] + sc[1][tid] + sc[2][tid] + sc[3][tid];
    int b = blockIdx.x >> 7;    // 128 blocks per graph
    atomicAdd(out + b*(H_+K_) + H_ + tid, s * (1.0f/N_));
  }
}

// ---------------- GEMM: C(16384 x 512) = A(16384 x Kdim) @ BT^T, m97-style staging ----------------
#define BM 128
#define BN 128
#define BK 32

__global__ __launch_bounds__(256) void k_gemm(
    const unsigned short* __restrict__ A, const unsigned short* __restrict__ BT,
    int Kdim, int mode, const float* __restrict__ bias, const float* __restrict__ Wpos,
    const float* __restrict__ positions, unsigned short* __restrict__ AB,
    float* __restrict__ out) {
  __shared__ unsigned short As[BM*BK];   // 8 KB, row-major stride 32 (unpadded: DMA layout)
  __shared__ unsigned short Bs[BN*BK];
  __shared__ float colsum[BN];
  int tid = threadIdx.x;
  int lane = tid & 63, wv = tid >> 6;
  int wm = wv >> 1, wn = wv & 1;
  int l15 = lane & 15, quad = lane >> 4;
  int bx = blockIdx.x;
  // bn-major: the 4 blocks sharing an A-tile are temporally adjacent -> L3 absorbs refetch
  int bm = bx >> 2, bn = bx & 3;
  int m0 = bm*BM, n0 = bn*BN;

  f32x4 acc[4][4] = {};

  int c = wv*2;
  int rowc = (lane >> 2), seg = lane & 3;
  const unsigned short* gA0 = A  + (size_t)(m0 + c*16 + rowc)*Kdim + seg*8;
  const unsigned short* gA1 = gA0 + (size_t)16*Kdim;
  const unsigned short* gB0 = BT + (size_t)(n0 + c*16 + rowc)*Kdim + seg*8;
  const unsigned short* gB1 = gB0 + (size_t)16*Kdim;
  unsigned short* lA0 = As + c*512;  // wave-uniform LDS base; DMA scatters lane*16B
  unsigned short* lA1 = lA0 + 512;
  unsigned short* lB0 = Bs + c*512;
  unsigned short* lB1 = lB0 + 512;

  int nk = Kdim / BK;
  for (int kt = 0; kt < nk; kt++) {
    __syncthreads();
    gl_lds16(gA0, lA0); gl_lds16(gA1, lA1);
    gl_lds16(gB0, lB0); gl_lds16(gB1, lB1);
    gA0 += BK; gA1 += BK; gB0 += BK; gB1 += BK;
    __syncthreads();

    bf16x8 aF[4], bF[4];
    #pragma unroll
    for (int f = 0; f < 4; f++)
      aF[f] = *(const bf16x8*)&As[(wm*64 + f*16 + l15)*BK + quad*8];
    #pragma unroll
    for (int f = 0; f < 4; f++)
      bF[f] = *(const bf16x8*)&Bs[(wn*64 + f*16 + l15)*BK + quad*8];
    #pragma unroll
    for (int mi = 0; mi < 4; mi++)
      #pragma unroll
      for (int ni = 0; ni < 4; ni++)
        acc[mi][ni] = __builtin_amdgcn_mfma_f32_16x16x32_bf16(aF[mi], bF[ni], acc[mi][ni], 0, 0, 0);
  }

  if (mode == 0) {
    float bz[4], w0v[4], w1v[4];
    #pragma unroll
    for (int ni = 0; ni < 4; ni++) {
      int gh = n0 + wn*64 + ni*16 + l15;
      bz[ni] = bias[gh]; w0v[ni] = Wpos[gh]; w1v[ni] = Wpos[H_ + gh];
    }
    #pragma unroll
    for (int mi = 0; mi < 4; mi++) {
      #pragma unroll
      for (int r = 0; r < 4; r++) {
        int gm = m0 + wm*64 + mi*16 + quad*4 + r;
        float2 p = ((const float2*)positions)[gm];
        #pragma unroll
        for (int ni = 0; ni < 4; ni++) {
          int gh = n0 + wn*64 + ni*16 + l15;
          float v = acc[mi][ni][r] + bz[ni] + p.x*w0v[ni] + p.y*w1v[ni];
          AB[(size_t)gm*1024 + 512 + gh] = f2bf(v);
        }
      }
    }
  } else {
    if (tid < BN) colsum[tid] = 0.f;
    __syncthreads();
    #pragma unroll
    for (int ni = 0; ni < 4; ni++) {
      float s = 0.f;
      #pragma unroll
      for (int mi = 0; mi < 4; mi++) {
        #pragma unroll
        for (int r = 0; r < 4; r++) s += fmaxf(acc[mi][ni][r], 0.f);
      }
      s += __shfl_down(s, 32);
      s += __shfl_down(s, 16);
      if (quad == 0) atomicAdd(&colsum[wn*64 + ni*16 + l15], s);
    }
    __syncthreads();
    if (tid < BN) {
      int b = m0 >> 12;
      atomicAdd(out + b*(H_+K_) + n0 + tid, colsum[tid] * (1.0f/N_));
    }
  }
}

// ---------------- K3: radius graph + mean aggregation, 8 dests/block, grid 2048 ----------------
__device__ __forceinline__ void acc8(uint4 v, float* a) {
  union { unsigned u; float f; } t;
  t.u = v.x << 16;          a[0] += fmaxf(t.f, 0.f);
  t.u = v.x & 0xFFFF0000u;  a[1] += fmaxf(t.f, 0.f);
  t.u = v.y << 16;          a[2] += fmaxf(t.f, 0.f);
  t.u = v.y & 0xFFFF0000u;  a[3] += fmaxf(t.f, 0.f);
  t.u = v.z << 16;          a[4] += fmaxf(t.f, 0.f);
  t.u = v.z & 0xFFFF0000u;  a[5] += fmaxf(t.f, 0.f);
  t.u = v.w << 16;          a[6] += fmaxf(t.f, 0.f);
  t.u = v.w & 0xFFFF0000u;  a[7] += fmaxf(t.f, 0.f);
}

__global__ __launch_bounds__(256) void k_aggregate(const float* __restrict__ positions,
                                                   unsigned short* __restrict__ AB) {
  __shared__ unsigned short nl[8*CAP];   // 3 KB
  __shared__ int cnt[8];
  __shared__ float sdx[8], sdy[8];
  int blk = blockIdx.x;                  // 0..2047
  int xcd = blk & 7;
  int b = xcd >> 1;                      // graph b pinned to XCDs {2b, 2b+1}
  int sub = ((blk >> 3) << 1) | (xcd & 1);   // 0..511
  int dest0 = sub * 8;
  int tid = threadIdx.x, lane = tid & 63, w = tid >> 6;
  const float2* p2 = (const float2*)(positions + (size_t)b*N_*2);
  if (tid < 8) {
    cnt[tid] = 0;
    float2 pd = p2[dest0 + tid];
    sdx[tid] = pd.x; sdy[tid] = pd.y;
  }
  __syncthreads();
  // phase 1: scan all positions, test 8 dests per src point
  for (int it = 0; it < 16; it++) {
    int j = tid + 256*it;
    float2 pj = p2[j];
    #pragma unroll
    for (int d = 0; d < 8; d++) {
      float dx = pj.x - sdx[d], dy = pj.y - sdy[d];
      if (dx*dx + dy*dy < R2_ && j != dest0 + d) {
        int p = atomicAdd(&cnt[d], 1);
        if (p < CAP) nl[d*CAP + p] = (unsigned short)j;
      }
    }
  }
  __syncthreads();
  // phase 2: wave w -> dests w*2, w*2+1; lane covers 8 of 512 cols; ILP-4 gather
  const unsigned short* featb = AB + ((size_t)(b << 12))*1024 + 512 + lane*8;
  #pragma unroll
  for (int dd = 0; dd < 2; dd++) {
    int d = w*2 + dd;
    int deg = cnt[d]; if (deg > CAP) deg = CAP;
    float inv = 1.0f / (float)(deg > 1 ? deg : 1);
    const unsigned short* nlp = &nl[d*CAP];
    float a[8] = {};
    int n = 0;
    for (; n + 4 <= deg; n += 4) {
      ushort4 idx = *(const ushort4*)&nlp[n];  // one ds_read_b64
      uint4 v0 = *(const uint4*)(featb + (size_t)idx.x*1024);
      uint4 v1 = *(const uint4*)(featb + (size_t)idx.y*1024);
      uint4 v2 = *(const uint4*)(featb + (size_t)idx.z*1024);
      uint4 v3 = *(const uint4*)(featb + (size_t)idx.w*1024);
      acc8(v0, a); acc8(v1, a); acc8(v2, a); acc8(v3, a);
    }
    for (; n < deg; n++) {
      int j = nlp[n];
      uint4 v = *(const uint4*)(featb + (size_t)j*1024);
      acc8(v, a);
    }
    uint4 o;
    o.x = ((unsigned)f2bf(a[1]*inv) << 16) | f2bf(a[0]*inv);
    o.y = ((unsigned)f2bf(a[3]*inv) << 16) | f2bf(a[2]*inv);
    o.z = ((unsigned)f2bf(a[5]*inv) << 16) | f2bf(a[4]*inv);
    o.w = ((unsigned)f2bf(a[7]*inv) << 16) | f2bf(a[6]*inv);
    *(uint4*)(AB + (size_t)((b << 12) + dest0 + d)*1024 + lane*8) = o;
  }
}

extern "C" void kernel_launch(void* const* d_in, const int* in_sizes, int n_in,
                              void* d_out, int out_size, void* d_ws, size_t ws_size,
                              hipStream_t stream) {
  const float* images    = (const float*)d_in[0];
  const float* positions = (const float*)d_in[1];
  const float* W_feat    = (const float*)d_in[2];
  const float* b_feat    = (const float*)d_in[3];
  const float* W_pos     = (const float*)d_in[4];
  const float* W_gnn     = (const float*)d_in[5];
  const float* W_self    = (const float*)d_in[6];
  const float* anchors   = (const float*)d_in[7];
  float* out = (float*)d_out;

  char* ws = (char*)d_ws;
  unsigned short* imgs_bf = (unsigned short*)ws;                     // 16384*1536*2 = 50331648
  unsigned short* AB      = (unsigned short*)(ws + 50331648);        // 16384*1024*2 = 33554432
  unsigned short* WfT     = (unsigned short*)(ws + 83886080);        // 512*1536*2  = 1572864
  unsigned short* WgsT    = (unsigned short*)(ws + 85458944);        // 512*1024*2  = 1048576
  float*          anorm   = (float*)(ws + 86507520);                 // 8*4

  hipMemsetAsync(d_out, 0, sizeof(float)*B_*(H_+K_), stream);
  k_prep<<<dim3(8, 41), 256, 0, stream>>>(W_feat, W_gnn, W_self, anchors, WfT, WgsT, anorm);
  k_concept_cast<<<M_/32, 256, 0, stream>>>(images, anchors, anorm, imgs_bf, out);
  k_gemm<<<512, 256, 0, stream>>>(imgs_bf, WfT, D_, 0, b_feat, W_pos, positions, AB, out);
  k_aggregate<<<2048, 256, 0, stream>>>(positions, AB);
  k_gemm<<<512, 256, 0, stream>>>(AB, WgsT, 1024, 1, nullptr, nullptr, nullptr, AB, out);
}

// Round 8
// 290.453 us; speedup vs baseline: 1.3249x; 1.0689x over previous
//
#include <hip/hip_runtime.h>

#define B_ 4
#define N_ 4096
#define D_ 1536
#define H_ 512
#define K_ 8
#define M_ (B_*N_)          // 16384
#define R2_ 160000.0f       // 400^2
#define CAP 192             // max neighbors tracked per node (mean deg ~32, P(>192)~0)

typedef __attribute__((ext_vector_type(8))) short bf16x8;
typedef __attribute__((ext_vector_type(4))) float f32x4;
typedef __attribute__((ext_vector_type(2))) float f32x2;

__device__ __forceinline__ unsigned short f2bf(float f) {
  union { float f; unsigned u; } v; v.f = f;
  unsigned r = (v.u + 0x7FFFu + ((v.u >> 16) & 1u)) >> 16;
  return (unsigned short)r;
}

typedef const __attribute__((address_space(1))) unsigned int gas_u32;
typedef __attribute__((address_space(3))) unsigned int las_u32;
__device__ __forceinline__ void gl_lds16(const unsigned short* g, unsigned short* l) {
  __builtin_amdgcn_global_load_lds((gas_u32*)g, (las_u32*)l, 16, 0, 0);
}

// ---------------- K0: prep — anchor norms + all weight transposes (one launch) ----------
__global__ __launch_bounds__(256) void k_prep(
    const float* __restrict__ Wf, const float* __restrict__ Wg, const float* __restrict__ Ws,
    const float* __restrict__ anchors, unsigned short* __restrict__ WfT,
    unsigned short* __restrict__ WgsT, float* __restrict__ anorm) {
  __shared__ float t[64][65];
  __shared__ float red[4];
  int bx = blockIdx.x, by = blockIdx.y, tid = threadIdx.x;
  if (by == 40) {
    int k = bx;
    float s = 0.f;
    for (int i = tid; i < D_; i += 256) { float v = anchors[k*D_ + i]; s += v*v; }
    #pragma unroll
    for (int off = 32; off; off >>= 1) s += __shfl_down(s, off);
    if ((tid & 63) == 0) red[tid >> 6] = s;
    __syncthreads();
    if (tid == 0) anorm[k] = fmaxf(sqrtf(red[0]+red[1]+red[2]+red[3]), 1e-12f);
    return;
  }
  const float* W; unsigned short* WT; int kt, outStride, outOff;
  if (by < 24)      { W = Wf; WT = WfT;  kt = by;      outStride = D_;   outOff = 0; }
  else if (by < 32) { W = Wg; WT = WgsT; kt = by - 24; outStride = 1024; outOff = 0; }
  else              { W = Ws; WT = WgsT; kt = by - 32; outStride = 1024; outOff = 512; }
  int tx = tid & 63, ty = tid >> 6;
  #pragma unroll
  for (int r = 0; r < 64; r += 4)
    t[ty + r][tx] = W[(size_t)(kt*64 + ty + r)*H_ + bx*64 + tx];
  __syncthreads();
  #pragma unroll
  for (int r = 0; r < 64; r += 4) {
    int n = bx*64 + ty + r;
    WT[(size_t)n*outStride + outOff + kt*64 + tx] = f2bf(t[tx][ty + r]);
  }
}

// ---------------- K1: concept scores + images f32->bf16 cast (LDS-staged anchors) ----------------
__global__ __launch_bounds__(256) void k_concept_cast(
    const float* __restrict__ images, const float* __restrict__ anchors,
    const float* __restrict__ anorm, unsigned short* __restrict__ imgs_bf,
    float* __restrict__ out) {
  __shared__ float sA[K_*D_];     // 48 KB
  __shared__ float sc[4][K_];
  int tid = threadIdx.x, lane = tid & 63, w = tid >> 6;
  {
    const float4* a4 = (const float4*)anchors;
    float4* sA4 = (float4*)sA;
    #pragma unroll
    for (int i = 0; i < 12; i++) sA4[tid + 256*i] = a4[tid + 256*i];
  }
  __syncthreads();
  float acc_k[K_] = {};
  for (int r = 0; r < 8; r++) {
    int gm = blockIdx.x*32 + w*8 + r;
    const float4* xrow = (const float4*)(images + (size_t)gm*D_);
    float nrm = 0.f; float dot[K_] = {};
    #pragma unroll
    for (int it = 0; it < 6; it++) {
      int j = lane + 64*it;
      float4 x = xrow[j];
      nrm += x.x*x.x + x.y*x.y + x.z*x.z + x.w*x.w;
      #pragma unroll
      for (int k = 0; k < K_; k++) {
        float4 a = *(const float4*)&sA[(size_t)(k*384 + j)*4];
        dot[k] += x.x*a.x + x.y*a.y + x.z*a.z + x.w*a.w;
      }
      ushort4 s;
      s.x = f2bf(x.x); s.y = f2bf(x.y); s.z = f2bf(x.z); s.w = f2bf(x.w);
      *(ushort4*)&imgs_bf[(size_t)gm*D_ + (size_t)j*4] = s;
    }
    #pragma unroll
    for (int off = 32; off; off >>= 1) {
      nrm += __shfl_down(nrm, off);
      #pragma unroll
      for (int k = 0; k < K_; k++) dot[k] += __shfl_down(dot[k], off);
    }
    if (lane == 0) {
      float inv = 1.0f / fmaxf(sqrtf(nrm), 1e-12f);
      #pragma unroll
      for (int k = 0; k < K_; k++) acc_k[k] += dot[k] * inv / anorm[k];
    }
  }
  if (lane == 0) {
    #pragma unroll
    for (int k = 0; k < K_; k++) sc[w][k] = acc_k[k];
  }
  __syncthreads();
  if (tid < K_) {
    float s = sc[0][tid] + sc[1][tid] + sc[2][tid] + sc[3][tid];
    int b = blockIdx.x >> 7;    // 128 blocks per graph
    atomicAdd(out + b*(H_+K_) + H_ + tid, s * (1.0f/N_));
  }
}

// ---------------- GEMM: C(16384 x 512) = A(16384 x Kdim) @ BT^T, m97-style staging ----------------
#define BM 128
#define BN 128
#define BK 32

__global__ __launch_bounds__(256) void k_gemm(
    const unsigned short* __restrict__ A, const unsigned short* __restrict__ BT,
    int Kdim, int mode, const float* __restrict__ bias, const float* __restrict__ Wpos,
    const float* __restrict__ positions, unsigned short* __restrict__ AB,
    float* __restrict__ out) {
  __shared__ unsigned short As[BM*BK];   // 8 KB, row-major stride 32 (unpadded: DMA layout)
  __shared__ unsigned short Bs[BN*BK];
  __shared__ float colsum[BN];
  int tid = threadIdx.x;
  int lane = tid & 63, wv = tid >> 6;
  int wm = wv >> 1, wn = wv & 1;
  int l15 = lane & 15, quad = lane >> 4;
  int bx = blockIdx.x;
  // bn-major: the 4 blocks sharing an A-tile are temporally adjacent -> L3 absorbs refetch
  int bm = bx >> 2, bn = bx & 3;
  int m0 = bm*BM, n0 = bn*BN;

  f32x4 acc[4][4] = {};

  int c = wv*2;
  int rowc = (lane >> 2), seg = lane & 3;
  const unsigned short* gA0 = A  + (size_t)(m0 + c*16 + rowc)*Kdim + seg*8;
  const unsigned short* gA1 = gA0 + (size_t)16*Kdim;
  const unsigned short* gB0 = BT + (size_t)(n0 + c*16 + rowc)*Kdim + seg*8;
  const unsigned short* gB1 = gB0 + (size_t)16*Kdim;
  unsigned short* lA0 = As + c*512;  // wave-uniform LDS base; DMA scatters lane*16B
  unsigned short* lA1 = lA0 + 512;
  unsigned short* lB0 = Bs + c*512;
  unsigned short* lB1 = lB0 + 512;

  int nk = Kdim / BK;
  for (int kt = 0; kt < nk; kt++) {
    __syncthreads();
    gl_lds16(gA0, lA0); gl_lds16(gA1, lA1);
    gl_lds16(gB0, lB0); gl_lds16(gB1, lB1);
    gA0 += BK; gA1 += BK; gB0 += BK; gB1 += BK;
    __syncthreads();

    bf16x8 aF[4], bF[4];
    #pragma unroll
    for (int f = 0; f < 4; f++)
      aF[f] = *(const bf16x8*)&As[(wm*64 + f*16 + l15)*BK + quad*8];
    #pragma unroll
    for (int f = 0; f < 4; f++)
      bF[f] = *(const bf16x8*)&Bs[(wn*64 + f*16 + l15)*BK + quad*8];
    #pragma unroll
    for (int mi = 0; mi < 4; mi++)
      #pragma unroll
      for (int ni = 0; ni < 4; ni++)
        acc[mi][ni] = __builtin_amdgcn_mfma_f32_16x16x32_bf16(aF[mi], bF[ni], acc[mi][ni], 0, 0, 0);
  }

  if (mode == 0) {
    float bz[4], w0v[4], w1v[4];
    #pragma unroll
    for (int ni = 0; ni < 4; ni++) {
      int gh = n0 + wn*64 + ni*16 + l15;
      bz[ni] = bias[gh]; w0v[ni] = Wpos[gh]; w1v[ni] = Wpos[H_ + gh];
    }
    #pragma unroll
    for (int mi = 0; mi < 4; mi++) {
      #pragma unroll
      for (int r = 0; r < 4; r++) {
        int gm = m0 + wm*64 + mi*16 + quad*4 + r;
        float2 p = ((const float2*)positions)[gm];
        #pragma unroll
        for (int ni = 0; ni < 4; ni++) {
          int gh = n0 + wn*64 + ni*16 + l15;
          float v = acc[mi][ni][r] + bz[ni] + p.x*w0v[ni] + p.y*w1v[ni];
          AB[(size_t)gm*1024 + 512 + gh] = f2bf(v);
        }
      }
    }
  } else {
    if (tid < BN) colsum[tid] = 0.f;
    __syncthreads();
    #pragma unroll
    for (int ni = 0; ni < 4; ni++) {
      float s = 0.f;
      #pragma unroll
      for (int mi = 0; mi < 4; mi++) {
        #pragma unroll
        for (int r = 0; r < 4; r++) s += fmaxf(acc[mi][ni][r], 0.f);
      }
      s += __shfl_down(s, 32);
      s += __shfl_down(s, 16);
      if (quad == 0) atomicAdd(&colsum[wn*64 + ni*16 + l15], s);
    }
    __syncthreads();
    if (tid < BN) {
      int b = m0 >> 12;
      atomicAdd(out + b*(H_+K_) + n0 + tid, colsum[tid] * (1.0f/N_));
    }
  }
}

// ---------------- K2b: quantize relu(feat)*1/64 -> fp8 e4m3 (gather source) ----------------
__global__ __launch_bounds__(256) void k_quant(const unsigned short* __restrict__ AB,
                                               unsigned char* __restrict__ P) {
  int g = blockIdx.x*256 + threadIdx.x;       // 0 .. 16384*64-1
  int row = g >> 6, cg = (g & 63)*8;
  uint4 v = *(const uint4*)(AB + (size_t)row*1024 + 512 + cg);
  float f[8];
  union { unsigned u; float x; } t;
  t.u = v.x << 16; f[0]=t.x; t.u = v.x & 0xFFFF0000u; f[1]=t.x;
  t.u = v.y << 16; f[2]=t.x; t.u = v.y & 0xFFFF0000u; f[3]=t.x;
  t.u = v.z << 16; f[4]=t.x; t.u = v.z & 0xFFFF0000u; f[5]=t.x;
  t.u = v.w << 16; f[6]=t.x; t.u = v.w & 0xFFFF0000u; f[7]=t.x;
  #pragma unroll
  for (int i = 0; i < 8; i++) f[i] = fminf(fmaxf(f[i], 0.f)*0.015625f, 448.f);
  int u0 = __builtin_amdgcn_cvt_pk_fp8_f32(f[0], f[1], 0, false);
  u0     = __builtin_amdgcn_cvt_pk_fp8_f32(f[2], f[3], u0, true);
  int u1 = __builtin_amdgcn_cvt_pk_fp8_f32(f[4], f[5], 0, false);
  u1     = __builtin_amdgcn_cvt_pk_fp8_f32(f[6], f[7], u1, true);
  uint2 o; o.x = (unsigned)u0; o.y = (unsigned)u1;
  *(uint2*)(P + (size_t)row*512 + cg) = o;
}

// ---------------- K3: radius graph + mean aggregation, fp8 gather ----------------
__device__ __forceinline__ void accf8(uint2 v, float* a) {
  f32x2 p;
  p = __builtin_amdgcn_cvt_pk_f32_fp8(v.x, false); a[0] += p[0]; a[1] += p[1];
  p = __builtin_amdgcn_cvt_pk_f32_fp8(v.x, true);  a[2] += p[0]; a[3] += p[1];
  p = __builtin_amdgcn_cvt_pk_f32_fp8(v.y, false); a[4] += p[0]; a[5] += p[1];
  p = __builtin_amdgcn_cvt_pk_f32_fp8(v.y, true);  a[6] += p[0]; a[7] += p[1];
}

__global__ __launch_bounds__(256) void k_aggregate(const float* __restrict__ positions,
                                                   const unsigned char* __restrict__ P,
                                                   unsigned short* __restrict__ AB) {
  __shared__ unsigned short nl[8*CAP];   // 3 KB
  __shared__ int cnt[8];
  __shared__ float sdx[8], sdy[8];
  int blk = blockIdx.x;                  // 0..2047
  int xcd = blk & 7;
  int b = xcd >> 1;                      // graph b pinned to XCDs {2b, 2b+1}
  int sub = ((blk >> 3) << 1) | (xcd & 1);   // 0..511
  int dest0 = sub * 8;
  int tid = threadIdx.x, lane = tid & 63, w = tid >> 6;
  const float2* p2 = (const float2*)(positions + (size_t)b*N_*2);
  if (tid < 8) {
    cnt[tid] = 0;
    float2 pd = p2[dest0 + tid];
    sdx[tid] = pd.x; sdy[tid] = pd.y;
  }
  __syncthreads();
  // phase 1: scan all positions, test 8 dests per src point
  for (int it = 0; it < 16; it++) {
    int j = tid + 256*it;
    float2 pj = p2[j];
    #pragma unroll
    for (int d = 0; d < 8; d++) {
      float dx = pj.x - sdx[d], dy = pj.y - sdy[d];
      if (dx*dx + dy*dy < R2_ && j != dest0 + d) {
        int p = atomicAdd(&cnt[d], 1);
        if (p < CAP) nl[d*CAP + p] = (unsigned short)j;
      }
    }
  }
  __syncthreads();
  // phase 2: wave w -> dests w*2, w*2+1; lane covers 8 of 512 cols; fp8 ILP-4 gather
  const unsigned char* featb = P + ((size_t)(b << 12))*512 + lane*8;
  #pragma unroll
  for (int dd = 0; dd < 2; dd++) {
    int d = w*2 + dd;
    int deg = cnt[d]; if (deg > CAP) deg = CAP;
    float inv = 64.0f / (float)(deg > 1 ? deg : 1);   // undo 1/64 quant scale
    const unsigned short* nlp = &nl[d*CAP];
    float a[8] = {};
    int n = 0;
    for (; n + 4 <= deg; n += 4) {
      ushort4 idx = *(const ushort4*)&nlp[n];  // one ds_read_b64
      uint2 v0 = *(const uint2*)(featb + (size_t)idx.x*512);
      uint2 v1 = *(const uint2*)(featb + (size_t)idx.y*512);
      uint2 v2 = *(const uint2*)(featb + (size_t)idx.z*512);
      uint2 v3 = *(const uint2*)(featb + (size_t)idx.w*512);
      accf8(v0, a); accf8(v1, a); accf8(v2, a); accf8(v3, a);
    }
    for (; n < deg; n++) {
      int j = nlp[n];
      uint2 v = *(const uint2*)(featb + (size_t)j*512);
      accf8(v, a);
    }
    uint4 o;
    o.x = ((unsigned)f2bf(a[1]*inv) << 16) | f2bf(a[0]*inv);
    o.y = ((unsigned)f2bf(a[3]*inv) << 16) | f2bf(a[2]*inv);
    o.z = ((unsigned)f2bf(a[5]*inv) << 16) | f2bf(a[4]*inv);
    o.w = ((unsigned)f2bf(a[7]*inv) << 16) | f2bf(a[6]*inv);
    *(uint4*)(AB + (size_t)((b << 12) + dest0 + d)*1024 + lane*8) = o;
  }
}

extern "C" void kernel_launch(void* const* d_in, const int* in_sizes, int n_in,
                              void* d_out, int out_size, void* d_ws, size_t ws_size,
                              hipStream_t stream) {
  const float* images    = (const float*)d_in[0];
  const float* positions = (const float*)d_in[1];
  const float* W_feat    = (const float*)d_in[2];
  const float* b_feat    = (const float*)d_in[3];
  const float* W_pos     = (const float*)d_in[4];
  const float* W_gnn     = (const float*)d_in[5];
  const float* W_self    = (const float*)d_in[6];
  const float* anchors   = (const float*)d_in[7];
  float* out = (float*)d_out;

  char* ws = (char*)d_ws;
  unsigned short* imgs_bf = (unsigned short*)ws;                     // 16384*1536*2 = 50331648 (dead after gemm1)
  unsigned char*  P       = (unsigned char*)ws;                      // 16384*512 fp8 = 8388608 (aliases imgs_bf; written after gemm1)
  unsigned short* AB      = (unsigned short*)(ws + 50331648);        // 16384*1024*2 = 33554432
  unsigned short* WfT     = (unsigned short*)(ws + 83886080);        // 512*1536*2  = 1572864
  unsigned short* WgsT    = (unsigned short*)(ws + 85458944);        // 512*1024*2  = 1048576
  float*          anorm   = (float*)(ws + 86507520);                 // 8*4

  hipMemsetAsync(d_out, 0, sizeof(float)*B_*(H_+K_), stream);
  k_prep<<<dim3(8, 41), 256, 0, stream>>>(W_feat, W_gnn, W_self, anchors, WfT, WgsT, anorm);
  k_concept_cast<<<M_/32, 256, 0, stream>>>(images, anchors, anorm, imgs_bf, out);
  k_gemm<<<512, 256, 0, stream>>>(imgs_bf, WfT, D_, 0, b_feat, W_pos, positions, AB, out);
  k_quant<<<4096, 256, 0, stream>>>(AB, P);
  k_aggregate<<<2048, 256, 0, stream>>>(positions, P, AB);
  k_gemm<<<512, 256, 0, stream>>>(AB, WgsT, 1024, 1, nullptr, nullptr, nullptr, AB, out);
}

// Round 9
// 288.735 us; speedup vs baseline: 1.3328x; 1.0059x over previous
//
#include <hip/hip_runtime.h>

#define B_ 4
#define N_ 4096
#define D_ 1536
#define H_ 512
#define K_ 8
#define M_ (B_*N_)          // 16384
#define R2_ 160000.0f       // 400^2
#define CAP 192             // max neighbors tracked per node (mean deg ~32, P(>192)~0)

typedef __attribute__((ext_vector_type(8))) short bf16x8;
typedef __attribute__((ext_vector_type(4))) float f32x4;
typedef __attribute__((ext_vector_type(2))) float f32x2;

__device__ __forceinline__ unsigned short f2bf(float f) {
  union { float f; unsigned u; } v; v.f = f;
  unsigned r = (v.u + 0x7FFFu + ((v.u >> 16) & 1u)) >> 16;
  return (unsigned short)r;
}

typedef const __attribute__((address_space(1))) unsigned int gas_u32;
typedef __attribute__((address_space(3))) unsigned int las_u32;
__device__ __forceinline__ void gl_lds16(const unsigned short* g, unsigned short* l) {
  __builtin_amdgcn_global_load_lds((gas_u32*)g, (las_u32*)l, 16, 0, 0);
}

// ---------------- K0: prep — anchor norms + all weight transposes (one launch) ----------
__global__ __launch_bounds__(256) void k_prep(
    const float* __restrict__ Wf, const float* __restrict__ Wg, const float* __restrict__ Ws,
    const float* __restrict__ anchors, unsigned short* __restrict__ WfT,
    unsigned short* __restrict__ WgsT, float* __restrict__ anorm) {
  __shared__ float t[64][65];
  __shared__ float red[4];
  int bx = blockIdx.x, by = blockIdx.y, tid = threadIdx.x;
  if (by == 40) {
    int k = bx;
    float s = 0.f;
    for (int i = tid; i < D_; i += 256) { float v = anchors[k*D_ + i]; s += v*v; }
    #pragma unroll
    for (int off = 32; off; off >>= 1) s += __shfl_down(s, off);
    if ((tid & 63) == 0) red[tid >> 6] = s;
    __syncthreads();
    if (tid == 0) anorm[k] = fmaxf(sqrtf(red[0]+red[1]+red[2]+red[3]), 1e-12f);
    return;
  }
  const float* W; unsigned short* WT; int kt, outStride, outOff;
  if (by < 24)      { W = Wf; WT = WfT;  kt = by;      outStride = D_;   outOff = 0; }
  else if (by < 32) { W = Wg; WT = WgsT; kt = by - 24; outStride = 1024; outOff = 0; }
  else              { W = Ws; WT = WgsT; kt = by - 32; outStride = 1024; outOff = 512; }
  int tx = tid & 63, ty = tid >> 6;
  #pragma unroll
  for (int r = 0; r < 64; r += 4)
    t[ty + r][tx] = W[(size_t)(kt*64 + ty + r)*H_ + bx*64 + tx];
  __syncthreads();
  #pragma unroll
  for (int r = 0; r < 64; r += 4) {
    int n = bx*64 + ty + r;
    WT[(size_t)n*outStride + outOff + kt*64 + tx] = f2bf(t[tx][ty + r]);
  }
}

// ---------------- K1: concept scores + images f32->bf16 cast (bf16 anchors in LDS) ----------------
__global__ __launch_bounds__(256) void k_concept_cast(
    const float* __restrict__ images, const float* __restrict__ anchors,
    const float* __restrict__ anorm, unsigned short* __restrict__ imgs_bf,
    float* __restrict__ out) {
  __shared__ unsigned short sAb[K_*D_];   // 24 KB bf16 anchors
  __shared__ float sc[4][K_];
  int tid = threadIdx.x, lane = tid & 63, w = tid >> 6;
  {
    const float4* a4 = (const float4*)anchors;
    #pragma unroll
    for (int i = 0; i < 12; i++) {
      float4 a = a4[tid + 256*i];
      ushort4 s; s.x = f2bf(a.x); s.y = f2bf(a.y); s.z = f2bf(a.z); s.w = f2bf(a.w);
      ((ushort4*)sAb)[tid + 256*i] = s;
    }
  }
  __syncthreads();
  float acc_k[K_] = {};
  for (int r = 0; r < 4; r++) {
    int gm = blockIdx.x*16 + w*4 + r;
    const float4* xrow = (const float4*)(images + (size_t)gm*D_);
    float nrm = 0.f; float dot[K_] = {};
    #pragma unroll
    for (int it = 0; it < 6; it++) {
      int j = lane + 64*it;
      float4 x = xrow[j];
      nrm += x.x*x.x + x.y*x.y + x.z*x.z + x.w*x.w;
      #pragma unroll
      for (int k = 0; k < K_; k++) {
        uint2 a = *(const uint2*)&sAb[k*D_ + j*4];
        union { unsigned u; float f; } c;
        float s = 0.f;
        c.u = a.x << 16;         s += x.x*c.f;
        c.u = a.x & 0xFFFF0000u; s += x.y*c.f;
        c.u = a.y << 16;         s += x.z*c.f;
        c.u = a.y & 0xFFFF0000u; s += x.w*c.f;
        dot[k] += s;
      }
      ushort4 s;
      s.x = f2bf(x.x); s.y = f2bf(x.y); s.z = f2bf(x.z); s.w = f2bf(x.w);
      *(ushort4*)&imgs_bf[(size_t)gm*D_ + (size_t)j*4] = s;
    }
    #pragma unroll
    for (int off = 32; off; off >>= 1) {
      nrm += __shfl_down(nrm, off);
      #pragma unroll
      for (int k = 0; k < K_; k++) dot[k] += __shfl_down(dot[k], off);
    }
    if (lane == 0) {
      float inv = 1.0f / fmaxf(sqrtf(nrm), 1e-12f);
      #pragma unroll
      for (int k = 0; k < K_; k++) acc_k[k] += dot[k] * inv / anorm[k];
    }
  }
  if (lane == 0) {
    #pragma unroll
    for (int k = 0; k < K_; k++) sc[w][k] = acc_k[k];
  }
  __syncthreads();
  if (tid < K_) {
    float s = sc[0][tid] + sc[1][tid] + sc[2][tid] + sc[3][tid];
    int b = blockIdx.x >> 8;    // 256 blocks per graph
    atomicAdd(out + b*(H_+K_) + H_ + tid, s * (1.0f/N_));
  }
}

// ---------------- GEMM: C(16384 x 512) = A(16384 x Kdim) @ BT^T, m97-style staging ----------------
#define BM 128
#define BN 128
#define BK 32

__global__ __launch_bounds__(256) void k_gemm(
    const unsigned short* __restrict__ A, const unsigned short* __restrict__ BT,
    int Kdim, int mode, const float* __restrict__ bias, const float* __restrict__ Wpos,
    const float* __restrict__ positions, unsigned short* __restrict__ AB,
    float* __restrict__ out) {
  __shared__ unsigned short As[BM*BK];   // 8 KB, row-major stride 32 (unpadded: DMA layout)
  __shared__ unsigned short Bs[BN*BK];
  __shared__ float colsum[BN];
  int tid = threadIdx.x;
  int lane = tid & 63, wv = tid >> 6;
  int wm = wv >> 1, wn = wv & 1;
  int l15 = lane & 15, quad = lane >> 4;
  int bx = blockIdx.x;
  // bn-major: the 4 blocks sharing an A-tile are temporally adjacent -> L3 absorbs refetch
  int bm = bx >> 2, bn = bx & 3;
  int m0 = bm*BM, n0 = bn*BN;

  f32x4 acc[4][4] = {};

  int c = wv*2;
  int rowc = (lane >> 2), seg = lane & 3;
  const unsigned short* gA0 = A  + (size_t)(m0 + c*16 + rowc)*Kdim + seg*8;
  const unsigned short* gA1 = gA0 + (size_t)16*Kdim;
  const unsigned short* gB0 = BT + (size_t)(n0 + c*16 + rowc)*Kdim + seg*8;
  const unsigned short* gB1 = gB0 + (size_t)16*Kdim;
  unsigned short* lA0 = As + c*512;  // wave-uniform LDS base; DMA scatters lane*16B
  unsigned short* lA1 = lA0 + 512;
  unsigned short* lB0 = Bs + c*512;
  unsigned short* lB1 = lB0 + 512;

  int nk = Kdim / BK;
  for (int kt = 0; kt < nk; kt++) {
    __syncthreads();
    gl_lds16(gA0, lA0); gl_lds16(gA1, lA1);
    gl_lds16(gB0, lB0); gl_lds16(gB1, lB1);
    gA0 += BK; gA1 += BK; gB0 += BK; gB1 += BK;
    __syncthreads();

    bf16x8 aF[4], bF[4];
    #pragma unroll
    for (int f = 0; f < 4; f++)
      aF[f] = *(const bf16x8*)&As[(wm*64 + f*16 + l15)*BK + quad*8];
    #pragma unroll
    for (int f = 0; f < 4; f++)
      bF[f] = *(const bf16x8*)&Bs[(wn*64 + f*16 + l15)*BK + quad*8];
    #pragma unroll
    for (int mi = 0; mi < 4; mi++)
      #pragma unroll
      for (int ni = 0; ni < 4; ni++)
        acc[mi][ni] = __builtin_amdgcn_mfma_f32_16x16x32_bf16(aF[mi], bF[ni], acc[mi][ni], 0, 0, 0);
  }

  if (mode == 0) {
    float bz[4], w0v[4], w1v[4];
    #pragma unroll
    for (int ni = 0; ni < 4; ni++) {
      int gh = n0 + wn*64 + ni*16 + l15;
      bz[ni] = bias[gh]; w0v[ni] = Wpos[gh]; w1v[ni] = Wpos[H_ + gh];
    }
    #pragma unroll
    for (int mi = 0; mi < 4; mi++) {
      #pragma unroll
      for (int r = 0; r < 4; r++) {
        int gm = m0 + wm*64 + mi*16 + quad*4 + r;
        float2 p = ((const float2*)positions)[gm];
        #pragma unroll
        for (int ni = 0; ni < 4; ni++) {
          int gh = n0 + wn*64 + ni*16 + l15;
          float v = acc[mi][ni][r] + bz[ni] + p.x*w0v[ni] + p.y*w1v[ni];
          AB[(size_t)gm*1024 + 512 + gh] = f2bf(v);
        }
      }
    }
  } else {
    if (tid < BN) colsum[tid] = 0.f;
    __syncthreads();
    #pragma unroll
    for (int ni = 0; ni < 4; ni++) {
      float s = 0.f;
      #pragma unroll
      for (int mi = 0; mi < 4; mi++) {
        #pragma unroll
        for (int r = 0; r < 4; r++) s += fmaxf(acc[mi][ni][r], 0.f);
      }
      s += __shfl_down(s, 32);
      s += __shfl_down(s, 16);
      if (quad == 0) atomicAdd(&colsum[wn*64 + ni*16 + l15], s);
    }
    __syncthreads();
    if (tid < BN) {
      int b = m0 >> 12;
      atomicAdd(out + b*(H_+K_) + n0 + tid, colsum[tid] * (1.0f/N_));
    }
  }
}

// ---------------- K2b: quantize relu(feat)*1/64 -> fp8 e4m3 (gather source) ----------------
__global__ __launch_bounds__(256) void k_quant(const unsigned short* __restrict__ AB,
                                               unsigned char* __restrict__ P) {
  int g = blockIdx.x*256 + threadIdx.x;       // 0 .. 16384*64-1
  int row = g >> 6, cg = (g & 63)*8;
  uint4 v = *(const uint4*)(AB + (size_t)row*1024 + 512 + cg);
  float f[8];
  union { unsigned u; float x; } t;
  t.u = v.x << 16; f[0]=t.x; t.u = v.x & 0xFFFF0000u; f[1]=t.x;
  t.u = v.y << 16; f[2]=t.x; t.u = v.y & 0xFFFF0000u; f[3]=t.x;
  t.u = v.z << 16; f[4]=t.x; t.u = v.z & 0xFFFF0000u; f[5]=t.x;
  t.u = v.w << 16; f[6]=t.x; t.u = v.w & 0xFFFF0000u; f[7]=t.x;
  #pragma unroll
  for (int i = 0; i < 8; i++) f[i] = fminf(fmaxf(f[i], 0.f)*0.015625f, 448.f);
  int u0 = __builtin_amdgcn_cvt_pk_fp8_f32(f[0], f[1], 0, false);
  u0     = __builtin_amdgcn_cvt_pk_fp8_f32(f[2], f[3], u0, true);
  int u1 = __builtin_amdgcn_cvt_pk_fp8_f32(f[4], f[5], 0, false);
  u1     = __builtin_amdgcn_cvt_pk_fp8_f32(f[6], f[7], u1, true);
  uint2 o; o.x = (unsigned)u0; o.y = (unsigned)u1;
  *(uint2*)(P + (size_t)row*512 + cg) = o;
}

// ---------------- K3: radius graph + mean aggregation, fp8 gather ----------------
__device__ __forceinline__ void accf8(uint2 v, float* a) {
  f32x2 p;
  p = __builtin_amdgcn_cvt_pk_f32_fp8(v.x, false); a[0] += p[0]; a[1] += p[1];
  p = __builtin_amdgcn_cvt_pk_f32_fp8(v.x, true);  a[2] += p[0]; a[3] += p[1];
  p = __builtin_amdgcn_cvt_pk_f32_fp8(v.y, false); a[4] += p[0]; a[5] += p[1];
  p = __builtin_amdgcn_cvt_pk_f32_fp8(v.y, true);  a[6] += p[0]; a[7] += p[1];
}

__global__ __launch_bounds__(256) void k_aggregate(const float* __restrict__ positions,
                                                   const unsigned char* __restrict__ P,
                                                   unsigned short* __restrict__ AB) {
  __shared__ unsigned short nl[8*CAP];   // 3 KB
  __shared__ int cnt[8];
  __shared__ float sdx[8], sdy[8];
  int blk = blockIdx.x;                  // 0..2047
  int xcd = blk & 7;
  int b = xcd >> 1;                      // graph b pinned to XCDs {2b, 2b+1}
  int sub = ((blk >> 3) << 1) | (xcd & 1);   // 0..511
  int dest0 = sub * 8;
  int tid = threadIdx.x, lane = tid & 63, w = tid >> 6;
  const float2* p2 = (const float2*)(positions + (size_t)b*N_*2);
  if (tid < 8) {
    cnt[tid] = 0;
    float2 pd = p2[dest0 + tid];
    sdx[tid] = pd.x; sdy[tid] = pd.y;
  }
  __syncthreads();
  // phase 1: scan all positions, test 8 dests per src point
  for (int it = 0; it < 16; it++) {
    int j = tid + 256*it;
    float2 pj = p2[j];
    #pragma unroll
    for (int d = 0; d < 8; d++) {
      float dx = pj.x - sdx[d], dy = pj.y - sdy[d];
      if (dx*dx + dy*dy < R2_ && j != dest0 + d) {
        int p = atomicAdd(&cnt[d], 1);
        if (p < CAP) nl[d*CAP + p] = (unsigned short)j;
      }
    }
  }
  __syncthreads();
  // phase 2: wave w -> dests w*2, w*2+1; lane covers 8 of 512 cols; fp8 ILP-4 gather
  const unsigned char* featb = P + ((size_t)(b << 12))*512 + lane*8;
  #pragma unroll
  for (int dd = 0; dd < 2; dd++) {
    int d = w*2 + dd;
    int deg = cnt[d]; if (deg > CAP) deg = CAP;
    float inv = 64.0f / (float)(deg > 1 ? deg : 1);   // undo 1/64 quant scale
    const unsigned short* nlp = &nl[d*CAP];
    float a[8] = {};
    int n = 0;
    for (; n + 4 <= deg; n += 4) {
      ushort4 idx = *(const ushort4*)&nlp[n];  // one ds_read_b64
      uint2 v0 = *(const uint2*)(featb + (size_t)idx.x*512);
      uint2 v1 = *(const uint2*)(featb + (size_t)idx.y*512);
      uint2 v2 = *(const uint2*)(featb + (size_t)idx.z*512);
      uint2 v3 = *(const uint2*)(featb + (size_t)idx.w*512);
      accf8(v0, a); accf8(v1, a); accf8(v2, a); accf8(v3, a);
    }
    for (; n < deg; n++) {
      int j = nlp[n];
      uint2 v = *(const uint2*)(featb + (size_t)j*512);
      accf8(v, a);
    }
    uint4 o;
    o.x = ((unsigned)f2bf(a[1]*inv) << 16) | f2bf(a[0]*inv);
    o.y = ((unsigned)f2bf(a[3]*inv) << 16) | f2bf(a[2]*inv);
    o.z = ((unsigned)f2bf(a[5]*inv) << 16) | f2bf(a[4]*inv);
    o.w = ((unsigned)f2bf(a[7]*inv) << 16) | f2bf(a[6]*inv);
    *(uint4*)(AB + (size_t)((b << 12) + dest0 + d)*1024 + lane*8) = o;
  }
}

extern "C" void kernel_launch(void* const* d_in, const int* in_sizes, int n_in,
                              void* d_out, int out_size, void* d_ws, size_t ws_size,
                              hipStream_t stream) {
  const float* images    = (const float*)d_in[0];
  const float* positions = (const float*)d_in[1];
  const float* W_feat    = (const float*)d_in[2];
  const float* b_feat    = (const float*)d_in[3];
  const float* W_pos     = (const float*)d_in[4];
  const float* W_gnn     = (const float*)d_in[5];
  const float* W_self    = (const float*)d_in[6];
  const float* anchors   = (const float*)d_in[7];
  float* out = (float*)d_out;

  char* ws = (char*)d_ws;
  unsigned short* imgs_bf = (unsigned short*)ws;                     // 16384*1536*2 = 50331648 (dead after gemm1)
  unsigned char*  P       = (unsigned char*)ws;                      // 16384*512 fp8 = 8388608 (aliases imgs_bf; written after gemm1)
  unsigned short* AB      = (unsigned short*)(ws + 50331648);        // 16384*1024*2 = 33554432
  unsigned short* WfT     = (unsigned short*)(ws + 83886080);        // 512*1536*2  = 1572864
  unsigned short* WgsT    = (unsigned short*)(ws + 85458944);        // 512*1024*2  = 1048576
  float*          anorm   = (float*)(ws + 86507520);                 // 8*4

  hipMemsetAsync(d_out, 0, sizeof(float)*B_*(H_+K_), stream);
  k_prep<<<dim3(8, 41), 256, 0, stream>>>(W_feat, W_gnn, W_self, anchors, WfT, WgsT, anorm);
  k_concept_cast<<<M_/16, 256, 0, stream>>>(images, anchors, anorm, imgs_bf, out);
  k_gemm<<<512, 256, 0, stream>>>(imgs_bf, WfT, D_, 0, b_feat, W_pos, positions, AB, out);
  k_quant<<<4096, 256, 0, stream>>>(AB, P);
  k_aggregate<<<2048, 256, 0, stream>>>(positions, P, AB);
  k_gemm<<<512, 256, 0, stream>>>(AB, WgsT, 1024, 1, nullptr, nullptr, nullptr, AB, out);
}